// Round 10
// baseline (389.147 us; speedup 1.0000x reference)
//
#include <hip/hip_runtime.h>
#include <hip/hip_bf16.h>

typedef unsigned int uint;
typedef unsigned short ushort;
typedef __attribute__((ext_vector_type(8))) short bf16x8;
typedef __attribute__((ext_vector_type(4))) float f32x4;
typedef __attribute__((ext_vector_type(2))) float f32x2;

__device__ __forceinline__ float2 bf2_to_f2(uint u){
  union {unsigned int i; float f;} a,b;
  a.i = (u & 0xffffu) << 16;
  b.i = u & 0xffff0000u;
  return make_float2(a.f, b.f);
}
__device__ __forceinline__ float b2f(ushort u){
  union{uint i; float f;} x; x.i = (uint)u << 16; return x.f;
}
__device__ __forceinline__ ushort bf16bits(float f){
  union{ __hip_bfloat16 h; ushort u;} x; x.h = __float2bfloat16(f); return x.u;
}
__device__ __forceinline__ uint pack_bf2(float x, float y){
  return ((uint)bf16bits(y)<<16) | (uint)bf16bits(x);
}

// ---------------- init ----------------

__global__ void k_init_h(const int* __restrict__ xn, const float* __restrict__ table,
                         ushort* __restrict__ hb, int n){
  int gid = blockIdx.x*blockDim.x + threadIdx.x;
  if (gid >= n*64) return;
  int node = gid >> 6, lp = gid & 63;
  int x0 = xn[2*node];
  int x1 = xn[2*node+1]; x1 = x1<0?0:(x1>19?19:x1);
  const float* tr = table + (size_t)(x0*20+x1)*128 + lp*2;
  reinterpret_cast<uint*>(hb)[(size_t)node*64 + lp] = pack_bf2(tr[0], tr[1]);
}

// ---------------- CSR build: atomic-free 2-pass bucket sort ----------------
__global__ __launch_bounds__(256) void k_bhist(const int* __restrict__ ei, int* __restrict__ scanarr, int E){
  __shared__ int h[256];
  h[threadIdx.x] = 0;
  __syncthreads();
  int chunk = (E + 255) >> 8;
  int s = blockIdx.x*chunk;
  int e = s + chunk; if (e > E) e = E;
  for (int i = s + threadIdx.x; i < e; i += 256)
    atomicAdd(&h[ei[E+i] >> 8], 1);
  __syncthreads();
  scanarr[threadIdx.x*256 + blockIdx.x] = h[threadIdx.x];
}

__global__ __launch_bounds__(256) void k_scan_block(const int* __restrict__ deg, int* __restrict__ rowstart,
                                                    int* __restrict__ bsum, int n){
  int tid = threadIdx.x;
  int gid = blockIdx.x*256 + tid;
  int lane = tid & 63, wv = tid >> 6;
  int v = (gid < n) ? deg[gid] : 0;
  int x = v;
  #pragma unroll
  for (int off=1; off<64; off<<=1){
    int t = __shfl_up(x, off);
    if (lane >= off) x += t;
  }
  __shared__ int wsum[4], woff[4];
  if (lane==63) wsum[wv] = x;
  __syncthreads();
  if (tid==0){
    int r = 0;
    for (int i=0;i<4;++i){ woff[i]=r; r += wsum[i]; }
    bsum[blockIdx.x] = r;
  }
  __syncthreads();
  if (gid < n) rowstart[gid] = x + woff[wv] - v;
}

__global__ __launch_bounds__(256) void k_scan_sums(int* __restrict__ bsum, int nb){
  int tid = threadIdx.x;
  int lane = tid&63, wv = tid>>6;
  int v = (tid<nb)?bsum[tid]:0;
  int x = v;
  #pragma unroll
  for (int off=1;off<64;off<<=1){ int t=__shfl_up(x,off); if(lane>=off) x+=t; }
  __shared__ int wsum[4], woff[4];
  if (lane==63) wsum[wv]=x;
  __syncthreads();
  if (tid==0){ int r=0; for(int i=0;i<4;++i){woff[i]=r;r+=wsum[i];} }
  __syncthreads();
  if (tid<nb) bsum[tid] = x + woff[wv] - v;
}

__global__ void k_scan_add(int* __restrict__ rowstart, const int* __restrict__ bsum, int n, int total){
  int gid = blockIdx.x*256 + threadIdx.x;
  if (gid < n) rowstart[gid] += bsum[blockIdx.x];
  if (gid == 0) rowstart[n] = total;
}

__global__ __launch_bounds__(256) void k_bscatter(const int* __restrict__ ei, const int* __restrict__ scanarr,
                                                  uint* __restrict__ ebuf, int E){
  __shared__ int cur[256];
  cur[threadIdx.x] = scanarr[threadIdx.x*256 + blockIdx.x];
  __syncthreads();
  int chunk = (E + 255) >> 8;
  int s = blockIdx.x*chunk;
  int e = s + chunk; if (e > E) e = E;
  for (int i = s + threadIdx.x; i < e; i += 256){
    int dst = ei[E+i], src = ei[i];
    int pos = atomicAdd(&cur[dst >> 8], 1);
    ebuf[pos] = ((uint)dst << 16) | (uint)src;
  }
}

__global__ __launch_bounds__(256) void k_bbuild(const uint* __restrict__ ebuf, const int* __restrict__ scanarr,
                                                int* __restrict__ rowstart, ushort* __restrict__ csr16,
                                                int E, int N){
  __shared__ int cnt[256];
  __shared__ int cur[256];
  __shared__ int wsum[4], woff[4];
  int t = threadIdx.x, b = blockIdx.x;
  int s = scanarr[b*256];
  int e = scanarr[(b+1)*256];
  cnt[t] = 0;
  __syncthreads();
  for (int i = s + t; i < e; i += 256)
    atomicAdd(&cnt[(ebuf[i] >> 16) & 255], 1);
  __syncthreads();
  int lane = t & 63, wv = t >> 6;
  int v = cnt[t];
  int x = v;
  #pragma unroll
  for (int off=1; off<64; off<<=1){
    int tt = __shfl_up(x, off);
    if (lane >= off) x += tt;
  }
  if (lane==63) wsum[wv] = x;
  __syncthreads();
  if (t==0){ int r=0; for (int i=0;i<4;++i){ woff[i]=r; r+=wsum[i]; } }
  __syncthreads();
  int pref = x + woff[wv] - v;
  int d = b*256 + t;
  if (d < N) rowstart[d] = s + pref;
  if (b==0 && t==0) rowstart[N] = E;
  cur[t] = s + pref;
  __syncthreads();
  for (int i = s + t; i < e; i += 256){
    uint ev = ebuf[i];
    int pos = atomicAdd(&cur[(ev >> 16) & 255], 1);
    csr16[pos] = (ushort)(ev & 0xffffu);
  }
}

// ---------------- fused weight/table prep ----------------
__global__ __launch_bounds__(256) void k_prep_all(
    const float* __restrict__ gatW, const float* __restrict__ attS, const float* __restrict__ attD,
    const float* __restrict__ Wq, const float* __restrict__ Wk,
    const float* __restrict__ Wv, const float* __restrict__ Ws,
    const float* __restrict__ bq, const float* __restrict__ bk,
    const float* __restrict__ bv, const float* __restrict__ bs,
    const float* __restrict__ emb, const float* __restrict__ demb,
    const float* __restrict__ projW, const float* __restrict__ projB,
    ushort* __restrict__ wt_gat, ushort* __restrict__ wt_qkvs,
    float* __restrict__ bias512, float* __restrict__ table){
  int blk = blockIdx.x, t = threadIdx.x;
  if (blk < 192){
    int i = blk*256 + t;
    int l = i >> 14, rem = i & 16383, c = rem >> 7, k = rem & 127;
    wt_gat[(size_t)l*18432 + c*128 + k] = bf16bits(gatW[l*16384 + k*128 + c]);
  } else if (blk < 216){
    int idx = (blk-192)*256 + t;
    int l = idx >> 11, i16 = (idx >> 7) & 15, k = idx & 127;
    float acc = 0.f;
    if (i16 < 8){
      int sd = i16 >> 2, hh = i16 & 3;
      const float* att = (sd ? attD : attS) + l*128 + hh*32;
      #pragma unroll 8
      for (int c=0;c<32;++c) acc += gatW[l*16384 + k*128 + hh*32 + c] * att[c];
    }
    wt_gat[(size_t)l*18432 + (128+i16)*128 + k] = bf16bits(acc);
  } else if (blk < 472){
    int i = (blk-216)*256 + t;
    int c = i >> 7, k = i & 127;
    const float* W; const float* B; int sc; float scale = 1.f;
    if (c < 128){ W = Wq; B = bq; sc = c; scale = 0.011048543456039805f; } // 1/(sqrt(32)*16)
    else if (c < 384){
      int ct = c >> 7, within = c & 127, cf = within >> 4, cl = within & 15;
      int m = cl + 16*((ct-1)*2 + (cf>>2));
      int wn = cf & 3;
      if (wn < 2){ W = Wk; B = bk; sc = 2*m + wn; }
      else       { W = Wv; B = bv; sc = 2*m + wn - 2; }
    } else { W = Ws; B = bs; sc = c - 384; }
    wt_qkvs[c*128 + k] = bf16bits(W[k*128 + sc] * scale);
    if (k == 0) bias512[c] = B[sc] * scale;
  } else {
    int idx = (blk-472)*256 + t;
    int combo = idx >> 7, d = idx & 127;
    int a = combo/20, b = combo - a*20;
    float acc = projB[d];
    #pragma unroll 8
    for (int i=0;i<32;++i) acc += emb[a*32+i]*projW[i*128+d];
    #pragma unroll 8
    for (int i=0;i<32;++i) acc += demb[b*32+i]*projW[(32+i)*128+d];
    table[combo*128+d] = acc;
  }
}

// ---------------- MFMA GEMM ----------------
template<int CT, int MODE>
__global__ __launch_bounds__(256) void k_gemm_mfma(const ushort* __restrict__ X,
        const ushort* __restrict__ Wt, const float* __restrict__ bias,
        void* __restrict__ Yq, uint* __restrict__ Ykv, ushort* __restrict__ Ysk,
        float* __restrict__ Asd, int n){
  constexpr int COLS = (MODE==1) ? 144 : 128;
  constexpr int NCF  = COLS/16;
  __shared__ ushort wl[COLS*136];
  const int t = threadIdx.x;
  const int w = t >> 6, lane = t & 63;
  const int cl = lane & 15, khi = lane >> 4;
  const int rbase = blockIdx.x*64;

  int arow = rbase + w*16 + cl; if (arow >= n) arow = n-1;
  const bf16x8* Xr = reinterpret_cast<const bf16x8*>(X + (size_t)arow*128);
  bf16x8 a0 = Xr[0+khi], a1 = Xr[4+khi], a2 = Xr[8+khi], a3 = Xr[12+khi];

  for (int ct=0; ct<CT; ++ct){
    const ushort* wsrc = Wt + (size_t)ct*16384;
    __syncthreads();
    for (int idx = t; idx < COLS*2; idx += 256){
      int col = idx >> 1, k0 = (idx & 1)*64;
      const bf16x8* src = reinterpret_cast<const bf16x8*>(wsrc + (size_t)col*128 + k0);
      bf16x8* dst = reinterpret_cast<bf16x8*>(wl + col*136 + k0);
      #pragma unroll
      for (int i=0;i<8;++i) dst[i] = src[i];
    }
    __syncthreads();

    f32x4 acc[NCF];
    #pragma unroll
    for (int cf=0;cf<NCF;++cf) acc[cf] = f32x4{0.f,0.f,0.f,0.f};

    #pragma unroll
    for (int ks=0; ks<4; ++ks){
      bf16x8 av = (ks==0)?a0:(ks==1)?a1:(ks==2)?a2:a3;
      #pragma unroll
      for (int cf=0; cf<NCF; ++cf){
        bf16x8 bv = *reinterpret_cast<const bf16x8*>(wl + (cf*16+cl)*136 + ks*32 + khi*8);
        acc[cf] = __builtin_amdgcn_mfma_f32_16x16x32_bf16(av, bv, acc[cf], 0, 0, 0);
      }
    }

    #pragma unroll
    for (int j=0;j<4;++j){
      int node = rbase + w*16 + khi*4 + j;
      if (node < n){
        if (MODE==1){
          unsigned char* Y8 = (unsigned char*)Yq;
          float f0 = acc[0][j]*16.f, f1 = acc[1][j]*16.f, f2 = acc[2][j]*16.f, f3 = acc[3][j]*16.f;
          float f4 = acc[4][j]*16.f, f5 = acc[5][j]*16.f, f6 = acc[6][j]*16.f, f7 = acc[7][j]*16.f;
          int d0 = __builtin_amdgcn_cvt_pk_fp8_f32(f0, f1, 0, false);
          d0     = __builtin_amdgcn_cvt_pk_fp8_f32(f2, f3, d0, true);
          int d1 = __builtin_amdgcn_cvt_pk_fp8_f32(f4, f5, 0, false);
          d1     = __builtin_amdgcn_cvt_pk_fp8_f32(f6, f7, d1, true);
          *reinterpret_cast<uint2*>(Y8 + (size_t)node*128 + cl*8) = make_uint2((uint)d0, (uint)d1);
          if (cl < 8) Asd[(size_t)node*8 + cl] = acc[8][j];
        } else {
          if (ct == 0 || ct == 3){
            ushort* Y = (ct == 0) ? (ushort*)Yq : Ysk;
            ushort* yr = Y + (size_t)node*128 + cl;
            #pragma unroll
            for (int cf=0;cf<8;++cf)
              yr[cf*16] = bf16bits(acc[cf][j] + bias[ct*128 + cf*16 + cl]);
          } else {
            #pragma unroll
            for (int g=0; g<2; ++g){
              float f0 = (acc[g*4+0][j] + bias[ct*128 + (g*4+0)*16 + cl])*16.f;
              float f1 = (acc[g*4+1][j] + bias[ct*128 + (g*4+1)*16 + cl])*16.f;
              float f2 = (acc[g*4+2][j] + bias[ct*128 + (g*4+2)*16 + cl])*16.f;
              float f3 = (acc[g*4+3][j] + bias[ct*128 + (g*4+3)*16 + cl])*16.f;
              int d = __builtin_amdgcn_cvt_pk_fp8_f32(f0, f1, 0, false);
              d     = __builtin_amdgcn_cvt_pk_fp8_f32(f2, f3, d, true);
              int m = cl + 16*((ct-1)*2 + g);
              Ykv[(size_t)node*64 + m] = (uint)d;
            }
          }
        }
      }
    }
  }
}

// ---------------- GAT aggregate: quarter-wave per edge, uint2 gathers ----------------
// lane l: qd=l>>4, i=l&15. Lane's uint2 covers cols cf*16+i (cf=0..7); head(cf)=cf>>1.
// Quarter qd processes edges p ≡ qd (mod 4); cross-quarter combine via shfl_xor(16,32).
__global__ __launch_bounds__(256) void k_gat_agg(const int* __restrict__ rowstart, const ushort* __restrict__ csr16,
              const unsigned char* __restrict__ hw8, const float* __restrict__ a_sd,
              const float* __restrict__ bias, ushort* __restrict__ hb, int n){
  __shared__ float4 lw[4][64];
  __shared__ ushort lsrc[4][64];
  int wv = threadIdx.x >> 6, l = threadIdx.x & 63;
  int node = blockIdx.x*4 + wv;
  if (node >= n) return;
  int qd = l >> 4, i = l & 15;
  int start = rowstart[node], end = rowstart[node+1];
  float4 as4 = *reinterpret_cast<const float4*>(a_sd + (size_t)node*8);
  float4 ad4 = *reinterpret_cast<const float4*>(a_sd + (size_t)node*8 + 4);
  const uint2* rows64 = reinterpret_cast<const uint2*>(hw8);

  float a0=0.f,a1=0.f,a2=0.f,a3=0.f,a4=0.f,a5=0.f,a6=0.f,a7=0.f;
  float s0=0.f,s1=0.f,s2=0.f,s3=0.f;
  if (qd == 0){
    // self-loop (not in CSR), added by quarter 0 only
    float c0 = as4.x + ad4.x; c0 = fmaxf(c0, 0.2f*c0);
    float c1 = as4.y + ad4.y; c1 = fmaxf(c1, 0.2f*c1);
    float c2 = as4.z + ad4.z; c2 = fmaxf(c2, 0.2f*c2);
    float c3 = as4.w + ad4.w; c3 = fmaxf(c3, 0.2f*c3);
    float w0 = __expf(fminf(c0,30.f));
    float w1 = __expf(fminf(c1,30.f));
    float w2 = __expf(fminf(c2,30.f));
    float w3 = __expf(fminf(c3,30.f));
    uint2 u = rows64[(size_t)node*16 + i];
    f32x2 f0 = __builtin_amdgcn_cvt_pk_f32_fp8((int)u.x, false);
    f32x2 f1 = __builtin_amdgcn_cvt_pk_f32_fp8((int)u.x, true);
    f32x2 f2 = __builtin_amdgcn_cvt_pk_f32_fp8((int)u.y, false);
    f32x2 f3 = __builtin_amdgcn_cvt_pk_f32_fp8((int)u.y, true);
    a0 = w0*f0.x; a1 = w0*f0.y; a2 = w1*f1.x; a3 = w1*f1.y;
    a4 = w2*f2.x; a5 = w2*f2.y; a6 = w3*f3.x; a7 = w3*f3.y;
    s0 = w0; s1 = w1; s2 = w2; s3 = w3;
  }

  for (int base = start; base < end; base += 64){
    int len = end - base; if (len > 64) len = 64;
    if (l < len){
      int sv = csr16[base + l];
      lsrc[wv][l] = (ushort)sv;
      float4 a4v = *reinterpret_cast<const float4*>(a_sd + (size_t)sv*8);
      float t0 = a4v.x + ad4.x; t0 = fmaxf(t0, 0.2f*t0);
      float t1 = a4v.y + ad4.y; t1 = fmaxf(t1, 0.2f*t1);
      float t2 = a4v.z + ad4.z; t2 = fmaxf(t2, 0.2f*t2);
      float t3 = a4v.w + ad4.w; t3 = fmaxf(t3, 0.2f*t3);
      float4 w4;
      w4.x = __expf(fminf(t0,30.f));
      w4.y = __expf(fminf(t1,30.f));
      w4.z = __expf(fminf(t2,30.f));
      w4.w = __expf(fminf(t3,30.f));
      lw[wv][l] = w4;
    }
    int p = qd;
    for (; p+12 < len; p += 16){
      int eA = lsrc[wv][p],    eB = lsrc[wv][p+4];
      int eC = lsrc[wv][p+8],  eD = lsrc[wv][p+12];
      uint2 uA = rows64[(size_t)eA*16 + i];
      uint2 uB = rows64[(size_t)eB*16 + i];
      uint2 uC = rows64[(size_t)eC*16 + i];
      uint2 uD = rows64[(size_t)eD*16 + i];
      float4 wA = lw[wv][p],   wB = lw[wv][p+4];
      float4 wC = lw[wv][p+8], wD = lw[wv][p+12];
      f32x2 f;
      f = __builtin_amdgcn_cvt_pk_f32_fp8((int)uA.x, false); a0 += wA.x*f.x; a1 += wA.x*f.y;
      f = __builtin_amdgcn_cvt_pk_f32_fp8((int)uA.x, true);  a2 += wA.y*f.x; a3 += wA.y*f.y;
      f = __builtin_amdgcn_cvt_pk_f32_fp8((int)uA.y, false); a4 += wA.z*f.x; a5 += wA.z*f.y;
      f = __builtin_amdgcn_cvt_pk_f32_fp8((int)uA.y, true);  a6 += wA.w*f.x; a7 += wA.w*f.y;
      f = __builtin_amdgcn_cvt_pk_f32_fp8((int)uB.x, false); a0 += wB.x*f.x; a1 += wB.x*f.y;
      f = __builtin_amdgcn_cvt_pk_f32_fp8((int)uB.x, true);  a2 += wB.y*f.x; a3 += wB.y*f.y;
      f = __builtin_amdgcn_cvt_pk_f32_fp8((int)uB.y, false); a4 += wB.z*f.x; a5 += wB.z*f.y;
      f = __builtin_amdgcn_cvt_pk_f32_fp8((int)uB.y, true);  a6 += wB.w*f.x; a7 += wB.w*f.y;
      f = __builtin_amdgcn_cvt_pk_f32_fp8((int)uC.x, false); a0 += wC.x*f.x; a1 += wC.x*f.y;
      f = __builtin_amdgcn_cvt_pk_f32_fp8((int)uC.x, true);  a2 += wC.y*f.x; a3 += wC.y*f.y;
      f = __builtin_amdgcn_cvt_pk_f32_fp8((int)uC.y, false); a4 += wC.z*f.x; a5 += wC.z*f.y;
      f = __builtin_amdgcn_cvt_pk_f32_fp8((int)uC.y, true);  a6 += wC.w*f.x; a7 += wC.w*f.y;
      f = __builtin_amdgcn_cvt_pk_f32_fp8((int)uD.x, false); a0 += wD.x*f.x; a1 += wD.x*f.y;
      f = __builtin_amdgcn_cvt_pk_f32_fp8((int)uD.x, true);  a2 += wD.y*f.x; a3 += wD.y*f.y;
      f = __builtin_amdgcn_cvt_pk_f32_fp8((int)uD.y, false); a4 += wD.z*f.x; a5 += wD.z*f.y;
      f = __builtin_amdgcn_cvt_pk_f32_fp8((int)uD.y, true);  a6 += wD.w*f.x; a7 += wD.w*f.y;
      s0 += (wA.x+wB.x)+(wC.x+wD.x);
      s1 += (wA.y+wB.y)+(wC.y+wD.y);
      s2 += (wA.z+wB.z)+(wC.z+wD.z);
      s3 += (wA.w+wB.w)+(wC.w+wD.w);
    }
    for (; p < len; p += 4){
      int eA = lsrc[wv][p];
      uint2 uA = rows64[(size_t)eA*16 + i];
      float4 wA = lw[wv][p];
      f32x2 f;
      f = __builtin_amdgcn_cvt_pk_f32_fp8((int)uA.x, false); a0 += wA.x*f.x; a1 += wA.x*f.y;
      f = __builtin_amdgcn_cvt_pk_f32_fp8((int)uA.x, true);  a2 += wA.y*f.x; a3 += wA.y*f.y;
      f = __builtin_amdgcn_cvt_pk_f32_fp8((int)uA.y, false); a4 += wA.z*f.x; a5 += wA.z*f.y;
      f = __builtin_amdgcn_cvt_pk_f32_fp8((int)uA.y, true);  a6 += wA.w*f.x; a7 += wA.w*f.y;
      s0 += wA.x; s1 += wA.y; s2 += wA.z; s3 += wA.w;
    }
  }
  // cross-quarter combine
  a0 += __shfl_xor(a0,16); a0 += __shfl_xor(a0,32);
  a1 += __shfl_xor(a1,16); a1 += __shfl_xor(a1,32);
  a2 += __shfl_xor(a2,16); a2 += __shfl_xor(a2,32);
  a3 += __shfl_xor(a3,16); a3 += __shfl_xor(a3,32);
  a4 += __shfl_xor(a4,16); a4 += __shfl_xor(a4,32);
  a5 += __shfl_xor(a5,16); a5 += __shfl_xor(a5,32);
  a6 += __shfl_xor(a6,16); a6 += __shfl_xor(a6,32);
  a7 += __shfl_xor(a7,16); a7 += __shfl_xor(a7,32);
  s0 += __shfl_xor(s0,16); s0 += __shfl_xor(s0,32);
  s1 += __shfl_xor(s1,16); s1 += __shfl_xor(s1,32);
  s2 += __shfl_xor(s2,16); s2 += __shfl_xor(s2,32);
  s3 += __shfl_xor(s3,16); s3 += __shfl_xor(s3,32);
  // quarter qd writes cf=2qd, 2qd+1 (head qd)
  float sh  = qd==0 ? s0 : qd==1 ? s1 : qd==2 ? s2 : s3;
  float acx = qd==0 ? a0 : qd==1 ? a2 : qd==2 ? a4 : a6;
  float acy = qd==0 ? a1 : qd==1 ? a3 : qd==2 ? a5 : a7;
  float inv = (1.f/16.f)/(sh + 1e-16f);
  int c0 = (2*qd)*16 + i;
  int c1 = c0 + 16;
  float o0 = acx*inv + bias[c0]; o0 = o0 > 0.f ? o0 : (__expf(o0)-1.f);
  float o1 = acy*inv + bias[c1]; o1 = o1 > 0.f ? o1 : (__expf(o1)-1.f);
  float hx = b2f(hb[(size_t)node*128 + c0]) + o0;
  float hy = b2f(hb[(size_t)node*128 + c1]) + o1;
  hb[(size_t)node*128 + c0] = bf16bits(hx);
  hb[(size_t)node*128 + c1] = bf16bits(hy);
}

// ---------------- transformer aggregate + fused layernorm (8-edge unroll) ----------------
__global__ __launch_bounds__(256) void k_trans_agg(const int* __restrict__ rowstart, const ushort* __restrict__ csr16,
              const ushort* __restrict__ yq, const uint* __restrict__ ykv,
              const ushort* __restrict__ ysk, const float* __restrict__ lng,
              const float* __restrict__ lnb, ushort* __restrict__ hb, int n){
  int wv = threadIdx.x>>6, lane = threadIdx.x&63;
  int node = blockIdx.x*4 + wv;
  if (node >= n) return;
  int li = lane & 15;
  bool odd1 = li & 1, odd2 = li & 2;
  int lbase = lane & 48;
  const uint* q32 = reinterpret_cast<const uint*>(yq);
  const uint* s32 = reinterpret_cast<const uint*>(ysk);
  uint* h32 = reinterpret_cast<uint*>(hb);
  float2 q2 = bf2_to_f2(q32[(size_t)node*64 + lane]);   // q pre-scaled by 1/(sqrt(32)*16)
  int start = rowstart[node], end = rowstart[node+1];
  float s = 0.f, s_tail = 0.f, ax = 0.f, ay = 0.f;
  int p = start;
  for (; p+7 < end; p += 8){
    int i0 = csr16[p],   i1 = csr16[p+1], i2 = csr16[p+2], i3 = csr16[p+3];
    int i4 = csr16[p+4], i5 = csr16[p+5], i6 = csr16[p+6], i7 = csr16[p+7];
    uint u0 = ykv[(size_t)i0*64 + lane];
    uint u1 = ykv[(size_t)i1*64 + lane];
    uint u2 = ykv[(size_t)i2*64 + lane];
    uint u3 = ykv[(size_t)i3*64 + lane];
    uint u4 = ykv[(size_t)i4*64 + lane];
    uint u5 = ykv[(size_t)i5*64 + lane];
    uint u6 = ykv[(size_t)i6*64 + lane];
    uint u7 = ykv[(size_t)i7*64 + lane];
    f32x2 k0 = __builtin_amdgcn_cvt_pk_f32_fp8((int)u0, false);
    f32x2 k1 = __builtin_amdgcn_cvt_pk_f32_fp8((int)u1, false);
    f32x2 k2 = __builtin_amdgcn_cvt_pk_f32_fp8((int)u2, false);
    f32x2 k3 = __builtin_amdgcn_cvt_pk_f32_fp8((int)u3, false);
    float p0 = q2.x*k0.x + q2.y*k0.y;
    float p1 = q2.x*k1.x + q2.y*k1.y;
    float p2 = q2.x*k2.x + q2.y*k2.y;
    float p3 = q2.x*k3.x + q2.y*k3.y;
    float aA = (odd1 ? p1 : p0) + __shfl_xor(odd1 ? p0 : p1, 1);
    float bA = (odd1 ? p3 : p2) + __shfl_xor(odd1 ? p2 : p3, 1);
    float cA = (odd2 ? bA : aA) + __shfl_xor(odd2 ? aA : bA, 2);
    cA += __shfl_xor(cA, 4);
    cA += __shfl_xor(cA, 8);
    float wA = __expf(fminf(cA, 30.f));
    f32x2 k4 = __builtin_amdgcn_cvt_pk_f32_fp8((int)u4, false);
    f32x2 k5 = __builtin_amdgcn_cvt_pk_f32_fp8((int)u5, false);
    f32x2 k6 = __builtin_amdgcn_cvt_pk_f32_fp8((int)u6, false);
    f32x2 k7 = __builtin_amdgcn_cvt_pk_f32_fp8((int)u7, false);
    float p4 = q2.x*k4.x + q2.y*k4.y;
    float p5 = q2.x*k5.x + q2.y*k5.y;
    float p6 = q2.x*k6.x + q2.y*k6.y;
    float p7 = q2.x*k7.x + q2.y*k7.y;
    float aB = (odd1 ? p5 : p4) + __shfl_xor(odd1 ? p4 : p5, 1);
    float bB = (odd1 ? p7 : p6) + __shfl_xor(odd1 ? p6 : p7, 1);
    float cB = (odd2 ? bB : aB) + __shfl_xor(odd2 ? aB : bB, 2);
    cB += __shfl_xor(cB, 4);
    cB += __shfl_xor(cB, 8);
    float wB = __expf(fminf(cB, 30.f));
    s += wA + wB;
    float w0 = __shfl(wA, lbase);
    float w1 = __shfl(wA, lbase|1);
    float w2 = __shfl(wA, lbase|2);
    float w3 = __shfl(wA, lbase|3);
    float w4 = __shfl(wB, lbase);
    float w5 = __shfl(wB, lbase|1);
    float w6 = __shfl(wB, lbase|2);
    float w7 = __shfl(wB, lbase|3);
    f32x2 v0 = __builtin_amdgcn_cvt_pk_f32_fp8((int)u0, true);
    f32x2 v1 = __builtin_amdgcn_cvt_pk_f32_fp8((int)u1, true);
    f32x2 v2 = __builtin_amdgcn_cvt_pk_f32_fp8((int)u2, true);
    f32x2 v3 = __builtin_amdgcn_cvt_pk_f32_fp8((int)u3, true);
    f32x2 v4 = __builtin_amdgcn_cvt_pk_f32_fp8((int)u4, true);
    f32x2 v5 = __builtin_amdgcn_cvt_pk_f32_fp8((int)u5, true);
    f32x2 v6 = __builtin_amdgcn_cvt_pk_f32_fp8((int)u6, true);
    f32x2 v7 = __builtin_amdgcn_cvt_pk_f32_fp8((int)u7, true);
    ax += w0*v0.x + w1*v1.x + w2*v2.x + w3*v3.x
        + w4*v4.x + w5*v5.x + w6*v6.x + w7*v7.x;
    ay += w0*v0.y + w1*v1.y + w2*v2.y + w3*v3.y
        + w4*v4.y + w5*v5.y + w6*v6.y + w7*v7.y;
  }
  for (; p+3 < end; p += 4){
    int i0 = csr16[p], i1 = csr16[p+1], i2 = csr16[p+2], i3 = csr16[p+3];
    uint u0 = ykv[(size_t)i0*64 + lane];
    uint u1 = ykv[(size_t)i1*64 + lane];
    uint u2 = ykv[(size_t)i2*64 + lane];
    uint u3 = ykv[(size_t)i3*64 + lane];
    f32x2 k0 = __builtin_amdgcn_cvt_pk_f32_fp8((int)u0, false);
    f32x2 k1 = __builtin_amdgcn_cvt_pk_f32_fp8((int)u1, false);
    f32x2 k2 = __builtin_amdgcn_cvt_pk_f32_fp8((int)u2, false);
    f32x2 k3 = __builtin_amdgcn_cvt_pk_f32_fp8((int)u3, false);
    float p0 = q2.x*k0.x + q2.y*k0.y;
    float p1 = q2.x*k1.x + q2.y*k1.y;
    float p2 = q2.x*k2.x + q2.y*k2.y;
    float p3 = q2.x*k3.x + q2.y*k3.y;
    float aA = (odd1 ? p1 : p0) + __shfl_xor(odd1 ? p0 : p1, 1);
    float bA = (odd1 ? p3 : p2) + __shfl_xor(odd1 ? p2 : p3, 1);
    float cA = (odd2 ? bA : aA) + __shfl_xor(odd2 ? aA : bA, 2);
    cA += __shfl_xor(cA, 4);
    cA += __shfl_xor(cA, 8);
    float w = __expf(fminf(cA, 30.f));
    s += w;
    float w0 = __shfl(w, lbase);
    float w1 = __shfl(w, lbase|1);
    float w2 = __shfl(w, lbase|2);
    float w3 = __shfl(w, lbase|3);
    f32x2 v0 = __builtin_amdgcn_cvt_pk_f32_fp8((int)u0, true);
    f32x2 v1 = __builtin_amdgcn_cvt_pk_f32_fp8((int)u1, true);
    f32x2 v2 = __builtin_amdgcn_cvt_pk_f32_fp8((int)u2, true);
    f32x2 v3 = __builtin_amdgcn_cvt_pk_f32_fp8((int)u3, true);
    ax += w0*v0.x + w1*v1.x + w2*v2.x + w3*v3.x;
    ay += w0*v0.y + w1*v1.y + w2*v2.y + w3*v3.y;
  }
  for (; p < end; ++p){
    int idx = csr16[p];
    uint u = ykv[(size_t)idx*64 + lane];
    f32x2 k2 = __builtin_amdgcn_cvt_pk_f32_fp8((int)u, false);
    float pr = q2.x*k2.x + q2.y*k2.y;
    pr += __shfl_xor(pr,1); pr += __shfl_xor(pr,2);
    pr += __shfl_xor(pr,4); pr += __shfl_xor(pr,8);
    float wt = __expf(fminf(pr, 30.f));
    f32x2 v2 = __builtin_amdgcn_cvt_pk_f32_fp8((int)u, true);
    s_tail += wt; ax += wt*v2.x; ay += wt*v2.y;
  }
  s += __shfl_xor(s, 1);
  s += __shfl_xor(s, 2);
  s += s_tail;
  float inv = (1.f/16.f)/(s + 1e-16f);       // fold out v's x16 scale
  int d = lane*2;
  float2 sk = bf2_to_f2(s32[(size_t)node*64 + lane]);
  float tx = ax*inv + sk.x;
  float ty = ay*inv + sk.y;
  tx = tx>0.f?tx:(__expf(tx)-1.f);
  ty = ty>0.f?ty:(__expf(ty)-1.f);
  float2 hp = bf2_to_f2(h32[(size_t)node*64 + lane]);
  hp.x += tx; hp.y += ty;
  float sm = hp.x + hp.y;
  #pragma unroll
  for (int m=1;m<64;m<<=1) sm += __shfl_xor(sm,m);
  float mu = sm * (1.f/128.f);
  float dx = hp.x-mu, dy = hp.y-mu;
  float vs = dx*dx + dy*dy;
  #pragma unroll
  for (int m=1;m<64;m<<=1) vs += __shfl_xor(vs,m);
  float r = rsqrtf(vs*(1.f/128.f) + 1e-5f);
  float2 gg = *reinterpret_cast<const float2*>(lng+d);
  float2 bb = *reinterpret_cast<const float2*>(lnb+d);
  h32[(size_t)node*64 + lane] = pack_bf2(dx*r*gg.x + bb.x, dy*r*gg.y + bb.y);
}

// ---------------- pooling (fused bounds search) ----------------
__global__ void k_pool(const ushort* __restrict__ hb, const int* __restrict__ batch,
                       float* __restrict__ out, int n, int G){
  int g = blockIdx.x, t = threadIdx.x;   // 64 threads
  int lo=0, hi=n;
  while (lo<hi){ int m=(lo+hi)>>1; if (batch[m] < g) lo=m+1; else hi=m; }
  int s = lo;
  lo=s; hi=n;
  while (lo<hi){ int m=(lo+hi)>>1; if (batch[m] < g+1) lo=m+1; else hi=m; }
  int e = lo;
  const uint* rows = reinterpret_cast<const uint*>(hb);
  float ax=0.f, ay=0.f;
  for (int i=s;i<e;++i){
    float2 f = bf2_to_f2(rows[(size_t)i*64 + t]);
    ax += f.x; ay += f.y;
  }
  float invc = 1.f / fmaxf((float)(e-s), 1.f);
  out[(size_t)g*128 + 2*t]   = ax*invc;
  out[(size_t)g*128 + 2*t+1] = ay*invc;
}

// ---------------- launch ----------------
extern "C" void kernel_launch(void* const* d_in, const int* in_sizes, int n_in,
                              void* d_out, int out_size, void* d_ws, size_t ws_size,
                              hipStream_t stream){
  const int* xn    = (const int*)d_in[0];
  const int* ei    = (const int*)d_in[1];
  const int* batch = (const int*)d_in[2];
  const float* emb  = (const float*)d_in[4];
  const float* demb = (const float*)d_in[5];
  const float* projW= (const float*)d_in[6];
  const float* projB= (const float*)d_in[7];
  const float* gatW = (const float*)d_in[8];
  const float* attS = (const float*)d_in[9];
  const float* attD = (const float*)d_in[10];
  const float* gatB = (const float*)d_in[11];
  const float* Wq = (const float*)d_in[12];
  const float* bq = (const float*)d_in[13];
  const float* Wk = (const float*)d_in[14];
  const float* bk = (const float*)d_in[15];
  const float* Wv = (const float*)d_in[16];
  const float* bv = (const float*)d_in[17];
  const float* Wsk= (const float*)d_in[18];
  const float* bsk= (const float*)d_in[19];
  const float* lng= (const float*)d_in[20];
  const float* lnb= (const float*)d_in[21];
  float* out = (float*)d_out;

  int N = in_sizes[0]/2;
  int E = in_sizes[1]/2;
  int G = out_size/128;

  char* w = (char*)d_ws;
  size_t off = 0;
  auto alloc = [&](size_t bytes)->char*{ char* p = w+off; off += (bytes + 255) & ~(size_t)255; return p; };
  ushort* hb   = (ushort*)alloc((size_t)N*128*2);   // h lives only as bf16
  ushort* yq   = (ushort*)alloc((size_t)N*128*2);   // q bf16; fp8 hw aliases its front half
  uint*   ykv  = (uint*)  alloc((size_t)N*64*4);    // fp8 kv quads
  ushort* ysk  = (ushort*)alloc((size_t)N*128*2);   // skip bf16
  unsigned char* hw8 = (unsigned char*)yq;
  float* a_sd = (float*)alloc((size_t)N*8*4);       // [node][a_s h0..3 | a_d h0..3]
  int* rowstart=(int*)alloc((size_t)(N+1)*4);
  uint* ebuf  = (uint*)alloc((size_t)E*4);          // bucketed (dst<<16|src)
  int* scanarr= (int*)alloc((size_t)(256*256+1)*4);
  ushort* csr16 = (ushort*)alloc((size_t)E*2);
  int* bsum   = (int*)alloc(4096);
  float* table= (float*)alloc(180*128*4);
  ushort* wt_gat  = (ushort*)alloc((size_t)3*144*128*2);
  ushort* wt_qkvs = (ushort*)alloc((size_t)512*128*2);
  float* bias512  = (float*)alloc(512*4);
  (void)ws_size; (void)n_in;

  // CSR build (atomic-free, LDS bucket sort)
  k_bhist<<<256,256,0,stream>>>(ei, scanarr, E);
  k_prep_all<<<562,256,0,stream>>>(gatW, attS, attD, Wq, Wk, Wv, Wsk,
                                   bq, bk, bv, bsk, emb, demb, projW, projB,
                                   wt_gat, wt_qkvs, bias512, table);
  k_init_h<<<(N*64+255)/256,256,0,stream>>>(xn, table, hb, N);
  k_scan_block<<<256,256,0,stream>>>(scanarr, scanarr, bsum, 256*256);
  k_scan_sums<<<1,256,0,stream>>>(bsum, 256);
  k_scan_add<<<256,256,0,stream>>>(scanarr, bsum, 256*256, E);
  k_bscatter<<<256,256,0,stream>>>(ei, scanarr, ebuf, E);
  k_bbuild<<<256,256,0,stream>>>(ebuf, scanarr, rowstart, csr16, E, N);

  int gemm_grid = (N+63)/64;
  for (int l=0;l<3;++l){
    k_gemm_mfma<1,1><<<gemm_grid,256,0,stream>>>(hb, wt_gat + (size_t)l*18432, nullptr,
                                                 hw8, nullptr, nullptr, a_sd, N);
    k_gat_agg<<<(N+3)/4,256,0,stream>>>(rowstart, csr16, hw8, a_sd, gatB + l*128, hb, N);
  }

  k_gemm_mfma<4,2><<<gemm_grid,256,0,stream>>>(hb, wt_qkvs, bias512, yq, ykv, ysk, nullptr, N);
  k_trans_agg<<<(N+3)/4,256,0,stream>>>(rowstart, csr16, yq, ykv, ysk, lng, lnb, hb, N);

  k_pool<<<G,64,0,stream>>>(hb, batch, out, N, G);
}

// Round 11
// 352.088 us; speedup vs baseline: 1.1053x; 1.1053x over previous
//
#include <hip/hip_runtime.h>
#include <hip/hip_bf16.h>

typedef unsigned int uint;
typedef unsigned short ushort;
typedef __attribute__((ext_vector_type(8))) short bf16x8;
typedef __attribute__((ext_vector_type(4))) float f32x4;
typedef __attribute__((ext_vector_type(2))) float f32x2;

__device__ __forceinline__ float2 bf2_to_f2(uint u){
  union {unsigned int i; float f;} a,b;
  a.i = (u & 0xffffu) << 16;
  b.i = u & 0xffff0000u;
  return make_float2(a.f, b.f);
}
__device__ __forceinline__ float b2f(ushort u){
  union{uint i; float f;} x; x.i = (uint)u << 16; return x.f;
}
__device__ __forceinline__ ushort bf16bits(float f){
  union{ __hip_bfloat16 h; ushort u;} x; x.h = __float2bfloat16(f); return x.u;
}
__device__ __forceinline__ uint pack_bf2(float x, float y){
  return ((uint)bf16bits(y)<<16) | (uint)bf16bits(x);
}

// ---------------- init ----------------

__global__ void k_init_h(const int* __restrict__ xn, const float* __restrict__ table,
                         ushort* __restrict__ hb, int n){
  int gid = blockIdx.x*blockDim.x + threadIdx.x;
  if (gid >= n*64) return;
  int node = gid >> 6, lp = gid & 63;
  int x0 = xn[2*node];
  int x1 = xn[2*node+1]; x1 = x1<0?0:(x1>19?19:x1);
  const float* tr = table + (size_t)(x0*20+x1)*128 + lp*2;
  reinterpret_cast<uint*>(hb)[(size_t)node*64 + lp] = pack_bf2(tr[0], tr[1]);
}

// ---------------- CSR build: atomic-free 2-pass bucket sort ----------------
__global__ __launch_bounds__(256) void k_bhist(const int* __restrict__ ei, int* __restrict__ scanarr, int E){
  __shared__ int h[256];
  h[threadIdx.x] = 0;
  __syncthreads();
  int chunk = (E + 255) >> 8;
  int s = blockIdx.x*chunk;
  int e = s + chunk; if (e > E) e = E;
  for (int i = s + threadIdx.x; i < e; i += 256)
    atomicAdd(&h[ei[E+i] >> 8], 1);
  __syncthreads();
  scanarr[threadIdx.x*256 + blockIdx.x] = h[threadIdx.x];
}

__global__ __launch_bounds__(256) void k_scan_block(const int* __restrict__ deg, int* __restrict__ rowstart,
                                                    int* __restrict__ bsum, int n){
  int tid = threadIdx.x;
  int gid = blockIdx.x*256 + tid;
  int lane = tid & 63, wv = tid >> 6;
  int v = (gid < n) ? deg[gid] : 0;
  int x = v;
  #pragma unroll
  for (int off=1; off<64; off<<=1){
    int t = __shfl_up(x, off);
    if (lane >= off) x += t;
  }
  __shared__ int wsum[4], woff[4];
  if (lane==63) wsum[wv] = x;
  __syncthreads();
  if (tid==0){
    int r = 0;
    for (int i=0;i<4;++i){ woff[i]=r; r += wsum[i]; }
    bsum[blockIdx.x] = r;
  }
  __syncthreads();
  if (gid < n) rowstart[gid] = x + woff[wv] - v;
}

__global__ __launch_bounds__(256) void k_scan_sums(int* __restrict__ bsum, int nb){
  int tid = threadIdx.x;
  int lane = tid&63, wv = tid>>6;
  int v = (tid<nb)?bsum[tid]:0;
  int x = v;
  #pragma unroll
  for (int off=1;off<64;off<<=1){ int t=__shfl_up(x,off); if(lane>=off) x+=t; }
  __shared__ int wsum[4], woff[4];
  if (lane==63) wsum[wv]=x;
  __syncthreads();
  if (tid==0){ int r=0; for(int i=0;i<4;++i){woff[i]=r;r+=wsum[i];} }
  __syncthreads();
  if (tid<nb) bsum[tid] = x + woff[wv] - v;
}

__global__ void k_scan_add(int* __restrict__ rowstart, const int* __restrict__ bsum, int n, int total){
  int gid = blockIdx.x*256 + threadIdx.x;
  if (gid < n) rowstart[gid] += bsum[blockIdx.x];
  if (gid == 0) rowstart[n] = total;
}

__global__ __launch_bounds__(256) void k_bscatter(const int* __restrict__ ei, const int* __restrict__ scanarr,
                                                  uint* __restrict__ ebuf, int E){
  __shared__ int cur[256];
  cur[threadIdx.x] = scanarr[threadIdx.x*256 + blockIdx.x];
  __syncthreads();
  int chunk = (E + 255) >> 8;
  int s = blockIdx.x*chunk;
  int e = s + chunk; if (e > E) e = E;
  for (int i = s + threadIdx.x; i < e; i += 256){
    int dst = ei[E+i], src = ei[i];
    int pos = atomicAdd(&cur[dst >> 8], 1);
    ebuf[pos] = ((uint)dst << 16) | (uint)src;
  }
}

__global__ __launch_bounds__(256) void k_bbuild(const uint* __restrict__ ebuf, const int* __restrict__ scanarr,
                                                int* __restrict__ rowstart, ushort* __restrict__ csr16,
                                                int E, int N){
  __shared__ int cnt[256];
  __shared__ int cur[256];
  __shared__ int wsum[4], woff[4];
  int t = threadIdx.x, b = blockIdx.x;
  int s = scanarr[b*256];
  int e = scanarr[(b+1)*256];
  cnt[t] = 0;
  __syncthreads();
  for (int i = s + t; i < e; i += 256)
    atomicAdd(&cnt[(ebuf[i] >> 16) & 255], 1);
  __syncthreads();
  int lane = t & 63, wv = t >> 6;
  int v = cnt[t];
  int x = v;
  #pragma unroll
  for (int off=1; off<64; off<<=1){
    int tt = __shfl_up(x, off);
    if (lane >= off) x += tt;
  }
  if (lane==63) wsum[wv] = x;
  __syncthreads();
  if (t==0){ int r=0; for (int i=0;i<4;++i){ woff[i]=r; r+=wsum[i]; } }
  __syncthreads();
  int pref = x + woff[wv] - v;
  int d = b*256 + t;
  if (d < N) rowstart[d] = s + pref;
  if (b==0 && t==0) rowstart[N] = E;
  cur[t] = s + pref;
  __syncthreads();
  for (int i = s + t; i < e; i += 256){
    uint ev = ebuf[i];
    int pos = atomicAdd(&cur[(ev >> 16) & 255], 1);
    csr16[pos] = (ushort)(ev & 0xffffu);
  }
}

// ---------------- fused weight/table prep ----------------
__global__ __launch_bounds__(256) void k_prep_all(
    const float* __restrict__ gatW, const float* __restrict__ attS, const float* __restrict__ attD,
    const float* __restrict__ Wq, const float* __restrict__ Wk,
    const float* __restrict__ Wv, const float* __restrict__ Ws,
    const float* __restrict__ bq, const float* __restrict__ bk,
    const float* __restrict__ bv, const float* __restrict__ bs,
    const float* __restrict__ emb, const float* __restrict__ demb,
    const float* __restrict__ projW, const float* __restrict__ projB,
    ushort* __restrict__ wt_gat, ushort* __restrict__ wt_qkvs,
    float* __restrict__ bias512, float* __restrict__ table){
  int blk = blockIdx.x, t = threadIdx.x;
  if (blk < 192){
    int i = blk*256 + t;
    int l = i >> 14, rem = i & 16383, c = rem >> 7, k = rem & 127;
    wt_gat[(size_t)l*18432 + c*128 + k] = bf16bits(gatW[l*16384 + k*128 + c]);
  } else if (blk < 216){
    int idx = (blk-192)*256 + t;
    int l = idx >> 11, i16 = (idx >> 7) & 15, k = idx & 127;
    float acc = 0.f;
    if (i16 < 8){
      int sd = i16 >> 2, hh = i16 & 3;
      const float* att = (sd ? attD : attS) + l*128 + hh*32;
      #pragma unroll 8
      for (int c=0;c<32;++c) acc += gatW[l*16384 + k*128 + hh*32 + c] * att[c];
    }
    wt_gat[(size_t)l*18432 + (128+i16)*128 + k] = bf16bits(acc);
  } else if (blk < 472){
    int i = (blk-216)*256 + t;
    int c = i >> 7, k = i & 127;
    const float* W; const float* B; int sc; float scale = 1.f;
    if (c < 128){ W = Wq; B = bq; sc = c; scale = 0.011048543456039805f; } // 1/(sqrt(32)*16)
    else if (c < 384){
      int ct = c >> 7, within = c & 127, cf = within >> 4, cl = within & 15;
      int m = cl + 16*((ct-1)*2 + (cf>>2));
      int wn = cf & 3;
      if (wn < 2){ W = Wk; B = bk; sc = 2*m + wn; }
      else       { W = Wv; B = bv; sc = 2*m + wn - 2; }
    } else { W = Ws; B = bs; sc = c - 384; }
    wt_qkvs[c*128 + k] = bf16bits(W[k*128 + sc] * scale);
    if (k == 0) bias512[c] = B[sc] * scale;
  } else {
    int idx = (blk-472)*256 + t;
    int combo = idx >> 7, d = idx & 127;
    int a = combo/20, b = combo - a*20;
    float acc = projB[d];
    #pragma unroll 8
    for (int i=0;i<32;++i) acc += emb[a*32+i]*projW[i*128+d];
    #pragma unroll 8
    for (int i=0;i<32;++i) acc += demb[b*32+i]*projW[(32+i)*128+d];
    table[combo*128+d] = acc;
  }
}

// ---------------- MFMA GEMM ----------------
template<int CT, int MODE>
__global__ __launch_bounds__(256) void k_gemm_mfma(const ushort* __restrict__ X,
        const ushort* __restrict__ Wt, const float* __restrict__ bias,
        void* __restrict__ Yq, uint* __restrict__ Ykv, ushort* __restrict__ Ysk,
        float* __restrict__ Asd, int n){
  constexpr int COLS = (MODE==1) ? 144 : 128;
  constexpr int NCF  = COLS/16;
  __shared__ ushort wl[COLS*136];
  const int t = threadIdx.x;
  const int w = t >> 6, lane = t & 63;
  const int cl = lane & 15, khi = lane >> 4;
  const int rbase = blockIdx.x*64;

  int arow = rbase + w*16 + cl; if (arow >= n) arow = n-1;
  const bf16x8* Xr = reinterpret_cast<const bf16x8*>(X + (size_t)arow*128);
  bf16x8 a0 = Xr[0+khi], a1 = Xr[4+khi], a2 = Xr[8+khi], a3 = Xr[12+khi];

  for (int ct=0; ct<CT; ++ct){
    const ushort* wsrc = Wt + (size_t)ct*16384;
    __syncthreads();
    for (int idx = t; idx < COLS*2; idx += 256){
      int col = idx >> 1, k0 = (idx & 1)*64;
      const bf16x8* src = reinterpret_cast<const bf16x8*>(wsrc + (size_t)col*128 + k0);
      bf16x8* dst = reinterpret_cast<bf16x8*>(wl + col*136 + k0);
      #pragma unroll
      for (int i=0;i<8;++i) dst[i] = src[i];
    }
    __syncthreads();

    f32x4 acc[NCF];
    #pragma unroll
    for (int cf=0;cf<NCF;++cf) acc[cf] = f32x4{0.f,0.f,0.f,0.f};

    #pragma unroll
    for (int ks=0; ks<4; ++ks){
      bf16x8 av = (ks==0)?a0:(ks==1)?a1:(ks==2)?a2:a3;
      #pragma unroll
      for (int cf=0; cf<NCF; ++cf){
        bf16x8 bv = *reinterpret_cast<const bf16x8*>(wl + (cf*16+cl)*136 + ks*32 + khi*8);
        acc[cf] = __builtin_amdgcn_mfma_f32_16x16x32_bf16(av, bv, acc[cf], 0, 0, 0);
      }
    }

    #pragma unroll
    for (int j=0;j<4;++j){
      int node = rbase + w*16 + khi*4 + j;
      if (node < n){
        if (MODE==1){
          unsigned char* Y8 = (unsigned char*)Yq;
          float f0 = acc[0][j]*16.f, f1 = acc[1][j]*16.f, f2 = acc[2][j]*16.f, f3 = acc[3][j]*16.f;
          float f4 = acc[4][j]*16.f, f5 = acc[5][j]*16.f, f6 = acc[6][j]*16.f, f7 = acc[7][j]*16.f;
          int d0 = __builtin_amdgcn_cvt_pk_fp8_f32(f0, f1, 0, false);
          d0     = __builtin_amdgcn_cvt_pk_fp8_f32(f2, f3, d0, true);
          int d1 = __builtin_amdgcn_cvt_pk_fp8_f32(f4, f5, 0, false);
          d1     = __builtin_amdgcn_cvt_pk_fp8_f32(f6, f7, d1, true);
          *reinterpret_cast<uint2*>(Y8 + (size_t)node*128 + cl*8) = make_uint2((uint)d0, (uint)d1);
          if (cl < 8) Asd[(size_t)node*8 + cl] = acc[8][j];
        } else {
          if (ct == 0 || ct == 3){
            ushort* Y = (ct == 0) ? (ushort*)Yq : Ysk;
            ushort* yr = Y + (size_t)node*128 + cl;
            #pragma unroll
            for (int cf=0;cf<8;++cf)
              yr[cf*16] = bf16bits(acc[cf][j] + bias[ct*128 + cf*16 + cl]);
          } else {
            #pragma unroll
            for (int g=0; g<2; ++g){
              float f0 = (acc[g*4+0][j] + bias[ct*128 + (g*4+0)*16 + cl])*16.f;
              float f1 = (acc[g*4+1][j] + bias[ct*128 + (g*4+1)*16 + cl])*16.f;
              float f2 = (acc[g*4+2][j] + bias[ct*128 + (g*4+2)*16 + cl])*16.f;
              float f3 = (acc[g*4+3][j] + bias[ct*128 + (g*4+3)*16 + cl])*16.f;
              int d = __builtin_amdgcn_cvt_pk_fp8_f32(f0, f1, 0, false);
              d     = __builtin_amdgcn_cvt_pk_fp8_f32(f2, f3, d, true);
              int m = cl + 16*((ct-1)*2 + g);
              Ykv[(size_t)node*64 + m] = (uint)d;
            }
          }
        }
      }
    }
  }
}

// ---------------- GAT aggregate: half-wave per edge, dword gathers (round-9 version) ----------------
__global__ __launch_bounds__(256) void k_gat_agg(const int* __restrict__ rowstart, const ushort* __restrict__ csr16,
              const unsigned char* __restrict__ hw8, const float* __restrict__ a_sd,
              const float* __restrict__ bias, ushort* __restrict__ hb, int n){
  __shared__ float4 lw[4][64];
  __shared__ ushort lsrc[4][64];
  int wv = threadIdx.x >> 6, l = threadIdx.x & 63;
  int node = blockIdx.x*4 + wv;
  if (node >= n) return;
  int b = l & 31, half = l >> 5;
  int h0 = (b & 1) * 2;
  int cl = b >> 1;
  int start = rowstart[node], end = rowstart[node+1];
  float4 ad4 = *reinterpret_cast<const float4*>(a_sd + (size_t)node*8 + 4);
  const uint* rows32 = reinterpret_cast<const uint*>(hw8);

  float a0=0.f,a1=0.f,a2=0.f,a3=0.f,sA=0.f,sB=0.f;
  if (half == 0){
    float adA = (h0==0) ? ad4.x : ad4.z;
    float adB = (h0==0) ? ad4.y : ad4.w;
    float scA = a_sd[(size_t)node*8 + h0]     + adA; scA = fmaxf(scA, 0.2f*scA);
    float scB = a_sd[(size_t)node*8 + h0 + 1] + adB; scB = fmaxf(scB, 0.2f*scB);
    float wA = __expf(fminf(scA,30.f));
    float wB = __expf(fminf(scB,30.f));
    uint u = rows32[(size_t)node*32 + b];
    f32x2 flo = __builtin_amdgcn_cvt_pk_f32_fp8((int)u, false);
    f32x2 fhi = __builtin_amdgcn_cvt_pk_f32_fp8((int)u, true);
    sA = wA; sB = wB;
    a0 = wA*flo.x; a1 = wA*flo.y; a2 = wB*fhi.x; a3 = wB*fhi.y;
  }

  const float* lwf = reinterpret_cast<const float*>(&lw[wv][0]);
  for (int base = start; base < end; base += 64){
    int len = end - base; if (len > 64) len = 64;
    if (l < len){
      int sv = csr16[base + l];
      lsrc[wv][l] = (ushort)sv;
      float4 a4 = *reinterpret_cast<const float4*>(a_sd + (size_t)sv*8);
      float s0 = a4.x + ad4.x; s0 = fmaxf(s0, 0.2f*s0);
      float s1 = a4.y + ad4.y; s1 = fmaxf(s1, 0.2f*s1);
      float s2 = a4.z + ad4.z; s2 = fmaxf(s2, 0.2f*s2);
      float s3 = a4.w + ad4.w; s3 = fmaxf(s3, 0.2f*s3);
      float4 w4;
      w4.x = __expf(fminf(s0,30.f));
      w4.y = __expf(fminf(s1,30.f));
      w4.z = __expf(fminf(s2,30.f));
      w4.w = __expf(fminf(s3,30.f));
      lw[wv][l] = w4;
    }
    int p = half;
    for (; p+6 < len; p += 8){
      int e0 = lsrc[wv][p], e1 = lsrc[wv][p+2], e2 = lsrc[wv][p+4], e3 = lsrc[wv][p+6];
      float2 w0 = *reinterpret_cast<const float2*>(lwf + p*4 + h0);
      float2 w1 = *reinterpret_cast<const float2*>(lwf + (p+2)*4 + h0);
      float2 w2 = *reinterpret_cast<const float2*>(lwf + (p+4)*4 + h0);
      float2 w3 = *reinterpret_cast<const float2*>(lwf + (p+6)*4 + h0);
      uint u0 = rows32[(size_t)e0*32 + b];
      uint u1 = rows32[(size_t)e1*32 + b];
      uint u2 = rows32[(size_t)e2*32 + b];
      uint u3 = rows32[(size_t)e3*32 + b];
      f32x2 f;
      f = __builtin_amdgcn_cvt_pk_f32_fp8((int)u0, false); a0 += w0.x*f.x; a1 += w0.x*f.y;
      f = __builtin_amdgcn_cvt_pk_f32_fp8((int)u0, true);  a2 += w0.y*f.x; a3 += w0.y*f.y;
      f = __builtin_amdgcn_cvt_pk_f32_fp8((int)u1, false); a0 += w1.x*f.x; a1 += w1.x*f.y;
      f = __builtin_amdgcn_cvt_pk_f32_fp8((int)u1, true);  a2 += w1.y*f.x; a3 += w1.y*f.y;
      f = __builtin_amdgcn_cvt_pk_f32_fp8((int)u2, false); a0 += w2.x*f.x; a1 += w2.x*f.y;
      f = __builtin_amdgcn_cvt_pk_f32_fp8((int)u2, true);  a2 += w2.y*f.x; a3 += w2.y*f.y;
      f = __builtin_amdgcn_cvt_pk_f32_fp8((int)u3, false); a0 += w3.x*f.x; a1 += w3.x*f.y;
      f = __builtin_amdgcn_cvt_pk_f32_fp8((int)u3, true);  a2 += w3.y*f.x; a3 += w3.y*f.y;
      sA += (w0.x+w1.x)+(w2.x+w3.x);
      sB += (w0.y+w1.y)+(w2.y+w3.y);
    }
    for (; p < len; p += 2){
      int e0 = lsrc[wv][p];
      float2 w0 = *reinterpret_cast<const float2*>(lwf + p*4 + h0);
      uint u0 = rows32[(size_t)e0*32 + b];
      f32x2 f;
      f = __builtin_amdgcn_cvt_pk_f32_fp8((int)u0, false); a0 += w0.x*f.x; a1 += w0.x*f.y;
      f = __builtin_amdgcn_cvt_pk_f32_fp8((int)u0, true);  a2 += w0.y*f.x; a3 += w0.y*f.y;
      sA += w0.x; sB += w0.y;
    }
  }
  a0 += __shfl_xor(a0,32); a1 += __shfl_xor(a1,32);
  a2 += __shfl_xor(a2,32); a3 += __shfl_xor(a3,32);
  sA += __shfl_xor(sA,32); sB += __shfl_xor(sB,32);
  float invA = (1.f/16.f)/(sA + 1e-16f);
  float invB = (1.f/16.f)/(sB + 1e-16f);
  float accx = half ? a2 : a0;
  float accy = half ? a3 : a1;
  float inv  = half ? invB : invA;
  int c0 = (h0*2 + half*2)*16 + cl;
  int c1 = c0 + 16;
  float o0 = accx*inv + bias[c0]; o0 = o0 > 0.f ? o0 : (__expf(o0)-1.f);
  float o1 = accy*inv + bias[c1]; o1 = o1 > 0.f ? o1 : (__expf(o1)-1.f);
  float hx = b2f(hb[(size_t)node*128 + c0]) + o0;
  float hy = b2f(hb[(size_t)node*128 + c1]) + o1;
  hb[(size_t)node*128 + c0] = bf16bits(hx);
  hb[(size_t)node*128 + c1] = bf16bits(hy);
}

// ---------------- transformer aggregate + fused layernorm (8-edge unroll) ----------------
__global__ __launch_bounds__(256) void k_trans_agg(const int* __restrict__ rowstart, const ushort* __restrict__ csr16,
              const ushort* __restrict__ yq, const uint* __restrict__ ykv,
              const ushort* __restrict__ ysk, const float* __restrict__ lng,
              const float* __restrict__ lnb, ushort* __restrict__ hb, int n){
  int wv = threadIdx.x>>6, lane = threadIdx.x&63;
  int node = blockIdx.x*4 + wv;
  if (node >= n) return;
  int li = lane & 15;
  bool odd1 = li & 1, odd2 = li & 2;
  int lbase = lane & 48;
  const uint* q32 = reinterpret_cast<const uint*>(yq);
  const uint* s32 = reinterpret_cast<const uint*>(ysk);
  uint* h32 = reinterpret_cast<uint*>(hb);
  float2 q2 = bf2_to_f2(q32[(size_t)node*64 + lane]);   // q pre-scaled by 1/(sqrt(32)*16)
  int start = rowstart[node], end = rowstart[node+1];
  float s = 0.f, s_tail = 0.f, ax = 0.f, ay = 0.f;
  int p = start;
  for (; p+7 < end; p += 8){
    int i0 = csr16[p],   i1 = csr16[p+1], i2 = csr16[p+2], i3 = csr16[p+3];
    int i4 = csr16[p+4], i5 = csr16[p+5], i6 = csr16[p+6], i7 = csr16[p+7];
    uint u0 = ykv[(size_t)i0*64 + lane];
    uint u1 = ykv[(size_t)i1*64 + lane];
    uint u2 = ykv[(size_t)i2*64 + lane];
    uint u3 = ykv[(size_t)i3*64 + lane];
    uint u4 = ykv[(size_t)i4*64 + lane];
    uint u5 = ykv[(size_t)i5*64 + lane];
    uint u6 = ykv[(size_t)i6*64 + lane];
    uint u7 = ykv[(size_t)i7*64 + lane];
    f32x2 k0 = __builtin_amdgcn_cvt_pk_f32_fp8((int)u0, false);
    f32x2 k1 = __builtin_amdgcn_cvt_pk_f32_fp8((int)u1, false);
    f32x2 k2 = __builtin_amdgcn_cvt_pk_f32_fp8((int)u2, false);
    f32x2 k3 = __builtin_amdgcn_cvt_pk_f32_fp8((int)u3, false);
    float p0 = q2.x*k0.x + q2.y*k0.y;
    float p1 = q2.x*k1.x + q2.y*k1.y;
    float p2 = q2.x*k2.x + q2.y*k2.y;
    float p3 = q2.x*k3.x + q2.y*k3.y;
    float aA = (odd1 ? p1 : p0) + __shfl_xor(odd1 ? p0 : p1, 1);
    float bA = (odd1 ? p3 : p2) + __shfl_xor(odd1 ? p2 : p3, 1);
    float cA = (odd2 ? bA : aA) + __shfl_xor(odd2 ? aA : bA, 2);
    cA += __shfl_xor(cA, 4);
    cA += __shfl_xor(cA, 8);
    float wA = __expf(fminf(cA, 30.f));
    f32x2 k4 = __builtin_amdgcn_cvt_pk_f32_fp8((int)u4, false);
    f32x2 k5 = __builtin_amdgcn_cvt_pk_f32_fp8((int)u5, false);
    f32x2 k6 = __builtin_amdgcn_cvt_pk_f32_fp8((int)u6, false);
    f32x2 k7 = __builtin_amdgcn_cvt_pk_f32_fp8((int)u7, false);
    float p4 = q2.x*k4.x + q2.y*k4.y;
    float p5 = q2.x*k5.x + q2.y*k5.y;
    float p6 = q2.x*k6.x + q2.y*k6.y;
    float p7 = q2.x*k7.x + q2.y*k7.y;
    float aB = (odd1 ? p5 : p4) + __shfl_xor(odd1 ? p4 : p5, 1);
    float bB = (odd1 ? p7 : p6) + __shfl_xor(odd1 ? p6 : p7, 1);
    float cB = (odd2 ? bB : aB) + __shfl_xor(odd2 ? aB : bB, 2);
    cB += __shfl_xor(cB, 4);
    cB += __shfl_xor(cB, 8);
    float wB = __expf(fminf(cB, 30.f));
    s += wA + wB;
    float w0 = __shfl(wA, lbase);
    float w1 = __shfl(wA, lbase|1);
    float w2 = __shfl(wA, lbase|2);
    float w3 = __shfl(wA, lbase|3);
    float w4 = __shfl(wB, lbase);
    float w5 = __shfl(wB, lbase|1);
    float w6 = __shfl(wB, lbase|2);
    float w7 = __shfl(wB, lbase|3);
    f32x2 v0 = __builtin_amdgcn_cvt_pk_f32_fp8((int)u0, true);
    f32x2 v1 = __builtin_amdgcn_cvt_pk_f32_fp8((int)u1, true);
    f32x2 v2 = __builtin_amdgcn_cvt_pk_f32_fp8((int)u2, true);
    f32x2 v3 = __builtin_amdgcn_cvt_pk_f32_fp8((int)u3, true);
    f32x2 v4 = __builtin_amdgcn_cvt_pk_f32_fp8((int)u4, true);
    f32x2 v5 = __builtin_amdgcn_cvt_pk_f32_fp8((int)u5, true);
    f32x2 v6 = __builtin_amdgcn_cvt_pk_f32_fp8((int)u6, true);
    f32x2 v7 = __builtin_amdgcn_cvt_pk_f32_fp8((int)u7, true);
    ax += w0*v0.x + w1*v1.x + w2*v2.x + w3*v3.x
        + w4*v4.x + w5*v5.x + w6*v6.x + w7*v7.x;
    ay += w0*v0.y + w1*v1.y + w2*v2.y + w3*v3.y
        + w4*v4.y + w5*v5.y + w6*v6.y + w7*v7.y;
  }
  for (; p+3 < end; p += 4){
    int i0 = csr16[p], i1 = csr16[p+1], i2 = csr16[p+2], i3 = csr16[p+3];
    uint u0 = ykv[(size_t)i0*64 + lane];
    uint u1 = ykv[(size_t)i1*64 + lane];
    uint u2 = ykv[(size_t)i2*64 + lane];
    uint u3 = ykv[(size_t)i3*64 + lane];
    f32x2 k0 = __builtin_amdgcn_cvt_pk_f32_fp8((int)u0, false);
    f32x2 k1 = __builtin_amdgcn_cvt_pk_f32_fp8((int)u1, false);
    f32x2 k2 = __builtin_amdgcn_cvt_pk_f32_fp8((int)u2, false);
    f32x2 k3 = __builtin_amdgcn_cvt_pk_f32_fp8((int)u3, false);
    float p0 = q2.x*k0.x + q2.y*k0.y;
    float p1 = q2.x*k1.x + q2.y*k1.y;
    float p2 = q2.x*k2.x + q2.y*k2.y;
    float p3 = q2.x*k3.x + q2.y*k3.y;
    float aA = (odd1 ? p1 : p0) + __shfl_xor(odd1 ? p0 : p1, 1);
    float bA = (odd1 ? p3 : p2) + __shfl_xor(odd1 ? p2 : p3, 1);
    float cA = (odd2 ? bA : aA) + __shfl_xor(odd2 ? aA : bA, 2);
    cA += __shfl_xor(cA, 4);
    cA += __shfl_xor(cA, 8);
    float w = __expf(fminf(cA, 30.f));
    s += w;
    float w0 = __shfl(w, lbase);
    float w1 = __shfl(w, lbase|1);
    float w2 = __shfl(w, lbase|2);
    float w3 = __shfl(w, lbase|3);
    f32x2 v0 = __builtin_amdgcn_cvt_pk_f32_fp8((int)u0, true);
    f32x2 v1 = __builtin_amdgcn_cvt_pk_f32_fp8((int)u1, true);
    f32x2 v2 = __builtin_amdgcn_cvt_pk_f32_fp8((int)u2, true);
    f32x2 v3 = __builtin_amdgcn_cvt_pk_f32_fp8((int)u3, true);
    ax += w0*v0.x + w1*v1.x + w2*v2.x + w3*v3.x;
    ay += w0*v0.y + w1*v1.y + w2*v2.y + w3*v3.y;
  }
  for (; p < end; ++p){
    int idx = csr16[p];
    uint u = ykv[(size_t)idx*64 + lane];
    f32x2 k2 = __builtin_amdgcn_cvt_pk_f32_fp8((int)u, false);
    float pr = q2.x*k2.x + q2.y*k2.y;
    pr += __shfl_xor(pr,1); pr += __shfl_xor(pr,2);
    pr += __shfl_xor(pr,4); pr += __shfl_xor(pr,8);
    float wt = __expf(fminf(pr, 30.f));
    f32x2 v2 = __builtin_amdgcn_cvt_pk_f32_fp8((int)u, true);
    s_tail += wt; ax += wt*v2.x; ay += wt*v2.y;
  }
  s += __shfl_xor(s, 1);
  s += __shfl_xor(s, 2);
  s += s_tail;
  float inv = (1.f/16.f)/(s + 1e-16f);       // fold out v's x16 scale
  int d = lane*2;
  float2 sk = bf2_to_f2(s32[(size_t)node*64 + lane]);
  float tx = ax*inv + sk.x;
  float ty = ay*inv + sk.y;
  tx = tx>0.f?tx:(__expf(tx)-1.f);
  ty = ty>0.f?ty:(__expf(ty)-1.f);
  float2 hp = bf2_to_f2(h32[(size_t)node*64 + lane]);
  hp.x += tx; hp.y += ty;
  float sm = hp.x + hp.y;
  #pragma unroll
  for (int m=1;m<64;m<<=1) sm += __shfl_xor(sm,m);
  float mu = sm * (1.f/128.f);
  float dx = hp.x-mu, dy = hp.y-mu;
  float vs = dx*dx + dy*dy;
  #pragma unroll
  for (int m=1;m<64;m<<=1) vs += __shfl_xor(vs,m);
  float r = rsqrtf(vs*(1.f/128.f) + 1e-5f);
  float2 gg = *reinterpret_cast<const float2*>(lng+d);
  float2 bb = *reinterpret_cast<const float2*>(lnb+d);
  h32[(size_t)node*64 + lane] = pack_bf2(dx*r*gg.x + bb.x, dy*r*gg.y + bb.y);
}

// ---------------- pooling (fused bounds search) ----------------
__global__ void k_pool(const ushort* __restrict__ hb, const int* __restrict__ batch,
                       float* __restrict__ out, int n, int G){
  int g = blockIdx.x, t = threadIdx.x;   // 64 threads
  int lo=0, hi=n;
  while (lo<hi){ int m=(lo+hi)>>1; if (batch[m] < g) lo=m+1; else hi=m; }
  int s = lo;
  lo=s; hi=n;
  while (lo<hi){ int m=(lo+hi)>>1; if (batch[m] < g+1) lo=m+1; else hi=m; }
  int e = lo;
  const uint* rows = reinterpret_cast<const uint*>(hb);
  float ax=0.f, ay=0.f;
  for (int i=s;i<e;++i){
    float2 f = bf2_to_f2(rows[(size_t)i*64 + t]);
    ax += f.x; ay += f.y;
  }
  float invc = 1.f / fmaxf((float)(e-s), 1.f);
  out[(size_t)g*128 + 2*t]   = ax*invc;
  out[(size_t)g*128 + 2*t+1] = ay*invc;
}

// ---------------- launch ----------------
extern "C" void kernel_launch(void* const* d_in, const int* in_sizes, int n_in,
                              void* d_out, int out_size, void* d_ws, size_t ws_size,
                              hipStream_t stream){
  const int* xn    = (const int*)d_in[0];
  const int* ei    = (const int*)d_in[1];
  const int* batch = (const int*)d_in[2];
  const float* emb  = (const float*)d_in[4];
  const float* demb = (const float*)d_in[5];
  const float* projW= (const float*)d_in[6];
  const float* projB= (const float*)d_in[7];
  const float* gatW = (const float*)d_in[8];
  const float* attS = (const float*)d_in[9];
  const float* attD = (const float*)d_in[10];
  const float* gatB = (const float*)d_in[11];
  const float* Wq = (const float*)d_in[12];
  const float* bq = (const float*)d_in[13];
  const float* Wk = (const float*)d_in[14];
  const float* bk = (const float*)d_in[15];
  const float* Wv = (const float*)d_in[16];
  const float* bv = (const float*)d_in[17];
  const float* Wsk= (const float*)d_in[18];
  const float* bsk= (const float*)d_in[19];
  const float* lng= (const float*)d_in[20];
  const float* lnb= (const float*)d_in[21];
  float* out = (float*)d_out;

  int N = in_sizes[0]/2;
  int E = in_sizes[1]/2;
  int G = out_size/128;

  char* w = (char*)d_ws;
  size_t off = 0;
  auto alloc = [&](size_t bytes)->char*{ char* p = w+off; off += (bytes + 255) & ~(size_t)255; return p; };
  ushort* hb   = (ushort*)alloc((size_t)N*128*2);   // h lives only as bf16
  ushort* yq   = (ushort*)alloc((size_t)N*128*2);   // q bf16; fp8 hw aliases its front half
  uint*   ykv  = (uint*)  alloc((size_t)N*64*4);    // fp8 kv quads
  ushort* ysk  = (ushort*)alloc((size_t)N*128*2);   // skip bf16
  unsigned char* hw8 = (unsigned char*)yq;
  float* a_sd = (float*)alloc((size_t)N*8*4);       // [node][a_s h0..3 | a_d h0..3]
  int* rowstart=(int*)alloc((size_t)(N+1)*4);
  uint* ebuf  = (uint*)alloc((size_t)E*4);          // bucketed (dst<<16|src)
  int* scanarr= (int*)alloc((size_t)(256*256+1)*4);
  ushort* csr16 = (ushort*)alloc((size_t)E*2);
  int* bsum   = (int*)alloc(4096);
  float* table= (float*)alloc(180*128*4);
  ushort* wt_gat  = (ushort*)alloc((size_t)3*144*128*2);
  ushort* wt_qkvs = (ushort*)alloc((size_t)512*128*2);
  float* bias512  = (float*)alloc(512*4);
  (void)ws_size; (void)n_in;

  // CSR build (atomic-free, LDS bucket sort)
  k_bhist<<<256,256,0,stream>>>(ei, scanarr, E);
  k_prep_all<<<562,256,0,stream>>>(gatW, attS, attD, Wq, Wk, Wv, Wsk,
                                   bq, bk, bv, bsk, emb, demb, projW, projB,
                                   wt_gat, wt_qkvs, bias512, table);
  k_init_h<<<(N*64+255)/256,256,0,stream>>>(xn, table, hb, N);
  k_scan_block<<<256,256,0,stream>>>(scanarr, scanarr, bsum, 256*256);
  k_scan_sums<<<1,256,0,stream>>>(bsum, 256);
  k_scan_add<<<256,256,0,stream>>>(scanarr, bsum, 256*256, E);
  k_bscatter<<<256,256,0,stream>>>(ei, scanarr, ebuf, E);
  k_bbuild<<<256,256,0,stream>>>(ebuf, scanarr, rowstart, csr16, E, N);

  int gemm_grid = (N+63)/64;
  for (int l=0;l<3;++l){
    k_gemm_mfma<1,1><<<gemm_grid,256,0,stream>>>(hb, wt_gat + (size_t)l*18432, nullptr,
                                                 hw8, nullptr, nullptr, a_sd, N);
    k_gat_agg<<<(N+3)/4,256,0,stream>>>(rowstart, csr16, hw8, a_sd, gatB + l*128, hb, N);
  }

  k_gemm_mfma<4,2><<<gemm_grid,256,0,stream>>>(hb, wt_qkvs, bias512, yq, ykv, ysk, nullptr, N);
  k_trans_agg<<<(N+3)/4,256,0,stream>>>(rowstart, csr16, yq, ykv, ysk, lng, lnb, hb, N);

  k_pool<<<G,64,0,stream>>>(hb, batch, out, N, G);
}